// Round 1
// baseline (887.800 us; speedup 1.0000x reference)
//
#include <hip/hip_runtime.h>

// DiffusionBlock: 20 steps of depthwise 3x3 stencil, reflect padding, on
// (16,2,1024,1024) fp32.
//
// Rewrite: LDS-free register-rolling pipeline. The stencil is a 5-point
// CROSS (corner weights are exactly 0 per make_stencil_weight; w_l==w_r,
// w_t==w_b symmetry was already assumed by the previous LDS kernel), so a
// fused K-step pipeline only needs horizontal neighbors of the MIDDLE row:
//   u_{s+1}[r] = w01*(u_s[r-1]+u_s[r+1]) + w10*(left+right) + w11*u_s[r]
// Each wave owns a 256-col swath (float4 per lane) and marches down rows,
// keeping a 2-row register window per stage (banks A/B, roles swap by row
// parity -> no rotation shuffling beyond OLD<-fresh). Horizontal halo via
// DPP wave_shr:1 / wave_shl:1 (pure VALU, zero LDS traffic). Column mirror
// at image cols 0/1023 patched by 2 loop-invariant cndmasks; row mirror at
// rows 0/1023 handled exactly in the generic head/tail phases.
// K=10 per launch, 2 launches. Bands of RB=64 output rows give
// 32 planes * 16 bands * 5 swaths = 2560 waves. No __syncthreads, no LDS.

#define IMG  1024
#define KF   10           // fused steps per launch
#define RB   64           // output rows per band
#define SW   232          // useful cols per swath (left/right margin 12 >= KF)
#define NSW  5            // 5*232 = 1160 >= 1024
#define LPAD 12           // left extension cols (>= KF, multiple of 4)
#define NB   (IMG/RB)     // 16 bands
#define NPL  32           // planes = 16 batch * 2 ch
#define WPL  (NB*NSW)     // 80 waves per plane
#define NWAVES (NPL*WPL)  // 2560

__device__ __forceinline__ float dpp_left(float v) {   // lane i <- lane i-1 (wave_shr:1)
    return __int_as_float(__builtin_amdgcn_update_dpp(
        __float_as_int(v), __float_as_int(v), 0x138, 0xf, 0xf, false));
}
__device__ __forceinline__ float dpp_right(float v) {  // lane i <- lane i+1 (wave_shl:1)
    return __int_as_float(__builtin_amdgcn_update_dpp(
        __float_as_int(v), __float_as_int(v), 0x130, 0xf, 0xf, false));
}

// One pipeline advance at absolute input row rv. OLD/NEW are the two bank
// arrays with roles swapped by caller each iteration. PF is the prefetch
// slot holding row rv (reloaded with row rv+2). GEN=1: activity checks +
// row-mirror patches (head/tail). GEN=0: straight-line steady state.
#define STEP(rv, OLD, NEW, PF, GEN) do {                                     \
    const int _r = (rv);                                                     \
    float4 C = PF;                                                           \
    if (_r + 2 <= in_hi)                                                     \
        PF = *(const float4*)(lp + (size_t)(_r + 2) * IMG);                  \
    bool prod = GEN ? (_r <= in_hi) : true;                                  \
    _Pragma("unroll")                                                        \
    for (int j = 1; j <= KF; ++j) {                                          \
        float4 Cn; bool pr = true;                                           \
        const int f = _r - j;                                                \
        bool act = true;                                                     \
        if (GEN) {                                                           \
            const int lo = max(ob - KF + j, 0);                              \
            const int hi = min(ob + RB - 1 + KF - j, IMG - 1);               \
            act = (f >= lo) && (f <= hi);                                    \
        }                                                                    \
        if (act) {                                                           \
            const float4 mid = NEW[j-1];                                     \
            float4 vs;                                                       \
            if (GEN && f == 0) {               /* u[-1] = u[1] = C */        \
                vs.x = C.x + C.x; vs.y = C.y + C.y;                          \
                vs.z = C.z + C.z; vs.w = C.w + C.w;                          \
            } else if (GEN && f == IMG - 1) {  /* u[1024] = u[1022] = OLD */ \
                const float4 o = OLD[j-1];                                   \
                vs.x = o.x + o.x; vs.y = o.y + o.y;                          \
                vs.z = o.z + o.z; vs.w = o.w + o.w;                          \
            } else {                                                         \
                const float4 o = OLD[j-1];                                   \
                vs.x = o.x + C.x; vs.y = o.y + C.y;                          \
                vs.z = o.z + C.z; vs.w = o.w + C.w;                          \
            }                                                                \
            float lf = dpp_left(mid.w);                                      \
            float rg = dpp_right(mid.x);                                     \
            if (is_cL) lf = mid.y;             /* col 0: mirror col 1 */     \
            if (is_cR) rg = mid.z;             /* col 1023: mirror 1022 */   \
            Cn.x = vs.x*w01 + (lf    + mid.y)*w10 + mid.x*w11;               \
            Cn.y = vs.y*w01 + (mid.x + mid.z)*w10 + mid.y*w11;               \
            Cn.z = vs.z*w01 + (mid.y + mid.w)*w10 + mid.z*w11;               \
            Cn.w = vs.w*w01 + (mid.z + rg   )*w10 + mid.w*w11;               \
        } else { pr = false; }                                               \
        if (prod) { OLD[j-1] = C; }   /* rotate stage j-1: fresh -> bank */  \
        C = Cn; prod = GEN ? pr : true;                                      \
    }                                                                        \
    if ((!GEN || prod) && st_ok)                                             \
        *(float4*)(op + (size_t)(_r - KF) * IMG) = C;                        \
} while (0)

__global__ __launch_bounds__(64, 4) void diff10(
    const float* __restrict__ src, float* __restrict__ dst,
    const float* __restrict__ wt)
{
    const int lane  = threadIdx.x;          // 64-thread block == one wave
    const int gw    = blockIdx.x;
    const int plane = gw / WPL;
    const int rem   = gw - plane * WPL;
    const int band  = rem / NSW;
    const int sw    = rem - band * NSW;

    const int ob  = band * RB;              // first output row of this band
    const int uc0 = sw * SW;                // first useful col of this swath
    const int c0  = uc0 - LPAD + 4 * lane;  // this lane's first col (may be <0)
    const int cld = min(max(c0, 0), IMG - 4); // clamped load col (garbage ok)

    const float* __restrict__ lp = src + (size_t)plane * IMG * IMG + cld;
    float* __restrict__       op = dst + (size_t)plane * IMG * IMG + cld;

    const float* w9 = wt + (size_t)(plane & 1) * 9;
    const float w01 = w9[1];   // vertical weight (== w9[7])
    const float w10 = w9[3];   // horizontal weight (== w9[5])
    const float w11 = w9[4];   // center weight (corners w9[0,2,6,8] are 0)

    const bool is_cL  = (c0 == 0);          // lane's .x is image col 0
    const bool is_cR  = (c0 == IMG - 4);    // lane's .w is image col 1023
    const bool st_ok  = (c0 >= uc0) && (c0 < uc0 + SW) && (c0 <= IMG - 4);

    const int r_lo  = max(ob - KF, 0);
    const int in_hi = min(ob + RB - 1 + KF, IMG - 1);
    const int r_hi  = ob + RB - 1 + KF;     // last pipeline iteration
    const int head_end = r_lo + 2 * KF - 1; // generic head: activation+top mirror
    const int st_end   = min(r_hi, IMG - 1);// steady end; tail drains (bottom band)

    float4 A[KF] = {}, B[KF] = {};          // 2-row banks for u_0..u_{KF-1}
    float4 p0, p1;                          // distance-2 row prefetch slots
    p0 = *(const float4*)(lp + (size_t)r_lo * IMG);
    p1 = (r_lo + 1 <= in_hi) ? *(const float4*)(lp + (size_t)(r_lo + 1) * IMG) : p0;

    // All three phase lengths are even and phase starts preserve parity,
    // so the (A,B)/(B,A) role alternation is consistent throughout.
    for (int r = r_lo; r <= head_end; r += 2) {
        STEP(r,     A, B, p0, 1);
        STEP(r + 1, B, A, p1, 1);
    }
    for (int r = head_end + 1; r <= st_end; r += 2) {
        STEP(r,     A, B, p0, 0);
        STEP(r + 1, B, A, p1, 0);
    }
    for (int r = st_end + 1; r <= r_hi; r += 2) {
        STEP(r,     A, B, p0, 1);
        STEP(r + 1, B, A, p1, 1);
    }
}

extern "C" void kernel_launch(void* const* d_in, const int* in_sizes, int n_in,
                              void* d_out, int out_size, void* d_ws, size_t ws_size,
                              hipStream_t stream) {
    const float* x  = (const float*)d_in[0];
    const float* wt = (const float*)d_in[1];
    float* out = (float*)d_out;
    float* ws  = (float*)d_ws;   // needs >= 128 MiB (one tensor copy)

    dim3 g(NWAVES), b(64);
    // 20 steps = 2 launches x 10 fused steps
    diff10<<<g, b, 0, stream>>>(x,  ws,  wt);
    diff10<<<g, b, 0, stream>>>(ws, out, wt);
}

// Round 2
// 393.719 us; speedup vs baseline: 2.2549x; 2.2549x over previous
//
#include <hip/hip_runtime.h>

// DiffusionBlock: 20 steps of depthwise 3x3 stencil, reflect padding, on
// (16,2,1024,1024) fp32.
//
// LDS-free register-rolling pipeline (5-point cross stencil: corner weights
// are exactly 0; w_l==w_r, w_t==w_b):
//   u_{s+1}[r] = w01*(u_s[r-1]+u_s[r+1]) + w10*(left+right) + w11*u_s[r]
// Each wave owns a 256-col swath (float4/lane) and marches down rows keeping
// a 2-row register window per fused stage. Horizontal halo via DPP
// wave_shr:1 / wave_shl:1 (pure VALU). Column mirror patched by per-lane
// cndmask; row mirror handled exactly in generic head/tail phases.
//
// ROUND 2 FIX: round 1 used float4 A[KF], B[KF] arrays -> compiler demoted
// them to scratch (VGPR_Count=64 < 80 needed; WRITE_SIZE 4.9x = spill
// traffic). Banks are now 20 NAMED float4 variables threaded through the
// stage macro by name, so scalar replacement is trivially guaranteed.
// __launch_bounds__(64,3) gives the allocator ~168 VGPR headroom.

#define IMG  1024
#define KF   10           // fused steps per launch
#define RB   64           // output rows per band
#define SW   232          // useful cols per swath (margins 12 >= KF)
#define NSW  5            // 5*232 = 1160 >= 1024
#define LPAD 12           // left extension cols (>= KF, multiple of 4)
#define NB   (IMG/RB)     // 16 bands
#define NPL  32           // planes = 16 batch * 2 ch
#define WPL  (NB*NSW)     // 80 waves per plane
#define NWAVES (NPL*WPL)  // 2560

__device__ __forceinline__ float dpp_left(float v) {   // lane i <- lane i-1 (wave_shr:1)
    return __int_as_float(__builtin_amdgcn_update_dpp(
        __float_as_int(v), __float_as_int(v), 0x138, 0xf, 0xf, false));
}
__device__ __forceinline__ float dpp_right(float v) {  // lane i <- lane i+1 (wave_shl:1)
    return __int_as_float(__builtin_amdgcn_update_dpp(
        __float_as_int(v), __float_as_int(v), 0x130, 0xf, 0xf, false));
}

// One fused stage: consumes C (= u_{j-1}[r-j+1], row below), bank OV
// (= u_{j-1}[r-j-1], row above), bank NV (= u_{j-1}[r-j], middle row);
// produces u_j[r-j] into C and rotates OV <- old C.
// GEN=1 adds activity gating + row-mirror patches (head/tail phases only).
#define STAGE(jj, OV, NV, GEN)                                               \
    {                                                                        \
        float4 Cn; bool pr = true;                                           \
        const int f = _r - (jj);                                             \
        bool act = true;                                                     \
        if (GEN) {                                                           \
            const int lo = max(ob - KF + (jj), 0);                           \
            const int hi = min(ob + RB - 1 + KF - (jj), IMG - 1);            \
            act = (f >= lo) && (f <= hi);                                    \
        }                                                                    \
        if (act) {                                                           \
            const float4 mid = NV;                                           \
            float4 vs;                                                       \
            if (GEN && f == 0) {               /* u[-1] = u[1] = C */        \
                vs.x = C.x + C.x; vs.y = C.y + C.y;                          \
                vs.z = C.z + C.z; vs.w = C.w + C.w;                          \
            } else if (GEN && f == IMG - 1) {  /* u[1024] = u[1022] = OV */  \
                vs.x = OV.x + OV.x; vs.y = OV.y + OV.y;                      \
                vs.z = OV.z + OV.z; vs.w = OV.w + OV.w;                      \
            } else {                                                         \
                vs.x = OV.x + C.x; vs.y = OV.y + C.y;                        \
                vs.z = OV.z + C.z; vs.w = OV.w + C.w;                        \
            }                                                                \
            float lf = dpp_left(mid.w);                                      \
            float rg = dpp_right(mid.x);                                     \
            if (is_cL) lf = mid.y;             /* col 0: mirror col 1 */     \
            if (is_cR) rg = mid.z;             /* col 1023: mirror 1022 */   \
            Cn.x = vs.x*w01 + (lf    + mid.y)*w10 + mid.x*w11;               \
            Cn.y = vs.y*w01 + (mid.x + mid.z)*w10 + mid.y*w11;               \
            Cn.z = vs.z*w01 + (mid.y + mid.w)*w10 + mid.z*w11;               \
            Cn.w = vs.w*w01 + (mid.z + rg   )*w10 + mid.w*w11;               \
        } else { pr = false; Cn = C; }                                       \
        if (prod) { OV = C; }                                                \
        C = Cn; prod = GEN ? pr : true;                                      \
    }

// One pipeline advance at absolute input row rv. PF (p0/p1) holds row rv,
// reloaded with row rv+2. Bank names passed explicitly (OLD,NEW per stage).
#define STEPN(rv, PF, GEN, O0,N0,O1,N1,O2,N2,O3,N3,O4,N4,                    \
                           O5,N5,O6,N6,O7,N7,O8,N8,O9,N9)                    \
    do {                                                                     \
        const int _r = (rv);                                                 \
        float4 C = PF;                                                       \
        if (_r + 2 <= in_hi)                                                 \
            PF = *(const float4*)(lp + (size_t)(_r + 2) * IMG);              \
        bool prod = GEN ? (_r <= in_hi) : true;                              \
        STAGE(1,  O0, N0, GEN)                                               \
        STAGE(2,  O1, N1, GEN)                                               \
        STAGE(3,  O2, N2, GEN)                                               \
        STAGE(4,  O3, N3, GEN)                                               \
        STAGE(5,  O4, N4, GEN)                                               \
        STAGE(6,  O5, N5, GEN)                                               \
        STAGE(7,  O6, N6, GEN)                                               \
        STAGE(8,  O7, N7, GEN)                                               \
        STAGE(9,  O8, N8, GEN)                                               \
        STAGE(10, O9, N9, GEN)                                               \
        if ((!GEN || prod) && st_ok)                                         \
            *(float4*)(op + (size_t)(_r - KF) * IMG) = C;                    \
    } while (0)

#define STEP_E(rv, GEN) STEPN(rv, p0, GEN, a0,b0,a1,b1,a2,b2,a3,b3,a4,b4,    \
                                           a5,b5,a6,b6,a7,b7,a8,b8,a9,b9)
#define STEP_O(rv, GEN) STEPN(rv, p1, GEN, b0,a0,b1,a1,b2,a2,b3,a3,b4,a4,    \
                                           b5,a5,b6,a6,b7,a7,b8,a8,b9,a9)

__global__ __launch_bounds__(64, 3) void diff10(
    const float* __restrict__ src, float* __restrict__ dst,
    const float* __restrict__ wt)
{
    const int lane  = threadIdx.x;          // 64-thread block == one wave
    const int gw    = blockIdx.x;
    const int plane = gw / WPL;
    const int rem   = gw - plane * WPL;
    const int band  = rem / NSW;
    const int sw    = rem - band * NSW;

    const int ob  = band * RB;              // first output row of this band
    const int uc0 = sw * SW;                // first useful col of this swath
    const int c0  = uc0 - LPAD + 4 * lane;  // this lane's first col (may be <0)
    const int cld = min(max(c0, 0), IMG - 4); // clamped load col (garbage ok)

    const float* __restrict__ lp = src + (size_t)plane * IMG * IMG + cld;
    float* __restrict__       op = dst + (size_t)plane * IMG * IMG + cld;

    const float* w9 = wt + (size_t)(plane & 1) * 9;
    const float w01 = w9[1];   // vertical weight (== w9[7])
    const float w10 = w9[3];   // horizontal weight (== w9[5])
    const float w11 = w9[4];   // center weight (corners are 0)

    const bool is_cL  = (c0 == 0);          // lane's .x is image col 0
    const bool is_cR  = (c0 == IMG - 4);    // lane's .w is image col 1023
    const bool st_ok  = (c0 >= uc0) && (c0 < uc0 + SW) && (c0 <= IMG - 4);

    const int r_lo  = max(ob - KF, 0);
    const int in_hi = min(ob + RB - 1 + KF, IMG - 1);
    const int r_hi  = ob + RB - 1 + KF;     // last pipeline iteration
    const int head_end = r_lo + 2 * KF - 1; // generic head (2*KF steps)
    const int st_end   = min(r_hi, IMG - 1);// steady end; tail drains

    // 2-row banks for stages u_0..u_9 — NAMED registers (never an array).
    float4 a0{}, a1{}, a2{}, a3{}, a4{}, a5{}, a6{}, a7{}, a8{}, a9{};
    float4 b0{}, b1{}, b2{}, b3{}, b4{}, b5{}, b6{}, b7{}, b8{}, b9{};

    float4 p0, p1;                          // distance-2 row prefetch slots
    p0 = *(const float4*)(lp + (size_t)r_lo * IMG);
    p1 = (r_lo + 1 <= in_hi) ? *(const float4*)(lp + (size_t)(r_lo + 1) * IMG) : p0;

    // Phase lengths are even and preserve the even/odd role alternation.
    for (int r = r_lo; r <= head_end; r += 2) {
        STEP_E(r,     1);
        STEP_O(r + 1, 1);
    }
    for (int r = head_end + 1; r <= st_end; r += 2) {
        STEP_E(r,     0);
        STEP_O(r + 1, 0);
    }
    for (int r = st_end + 1; r <= r_hi; r += 2) {
        STEP_E(r,     1);
        STEP_O(r + 1, 1);
    }
}

extern "C" void kernel_launch(void* const* d_in, const int* in_sizes, int n_in,
                              void* d_out, int out_size, void* d_ws, size_t ws_size,
                              hipStream_t stream) {
    const float* x  = (const float*)d_in[0];
    const float* wt = (const float*)d_in[1];
    float* out = (float*)d_out;
    float* ws  = (float*)d_ws;   // needs >= 128 MiB (one tensor copy)

    dim3 g(NWAVES), b(64);
    // 20 steps = 2 launches x 10 fused steps
    diff10<<<g, b, 0, stream>>>(x,  ws,  wt);
    diff10<<<g, b, 0, stream>>>(ws, out, wt);
}